// Round 1
// baseline (3234.473 us; speedup 1.0000x reference)
//
#include <hip/hip_runtime.h>
#include <hip/hip_bf16.h>

// NonLocalBlock2D: x[8,256,64,64] fp32
//   theta/phi/g = 1x1 conv (C=256 -> IC=128)
//   f[n][m] = theta[n]·phi[m]; P = softmax over n (per column m)
//   y[n] = sum_m P[n][m] g[m];  out = W·y + b + x
// Pipeline (per batch for the big N×N stage, f buffer reused):
//   k_proj   : split-bf16 projections  theta_{hi,lo}[b][n][c], phi_{hi,lo}[b][m][c], gT[b][c][m]
//   k_gemm1  : f[n][m] fp32 via 3-pass split-bf16 MFMA (64x64/wave tiles)
//   k_stats  : colmax[m], colrcp[m]=1/sum_n exp(f-colmax)
//   k_gemm2  : yT partials[kc][c][n] = sum_{m in chunk} gT[c][m]·P[n][m] (P from f on the fly)
//   k_reduce : yT[b][c][n] bf16 = sum_kc partials
//   k_conv   : out = W(bf16)·yT(bf16) + Wb + x   (fp32 accum)

#define IC   128
#define CIN  256
#define NPOS 4096
#define NB   8

typedef __attribute__((ext_vector_type(8))) short bf16x8;
typedef __attribute__((ext_vector_type(4))) float f32x4;
typedef __attribute__((ext_vector_type(4))) float fvec4;

#define MFMA(a, b, c) __builtin_amdgcn_mfma_f32_16x16x32_bf16((a), (b), (c), 0, 0, 0)

static __device__ inline unsigned short f2bf(float f) {
    unsigned int u = __builtin_bit_cast(unsigned int, f);
    u += 0x7fffu + ((u >> 16) & 1u);   // RNE
    return (unsigned short)(u >> 16);
}
static __device__ inline float bf2f(unsigned short u) {
    unsigned int v = ((unsigned int)u) << 16;
    return __builtin_bit_cast(float, v);
}
static __device__ inline void splitbf(float v, unsigned short& hi, unsigned short& lo) {
    hi = f2bf(v);
    lo = f2bf(v - bf2f(hi));
}

// ---------------- projections: out[c][n] = sum_k w[c][k] x[k][n] + bias[c] ----------------
__global__ __launch_bounds__(256) void k_proj(
    const float* __restrict__ x,
    const float* __restrict__ gw, const float* __restrict__ gb,
    const float* __restrict__ tw, const float* __restrict__ tb,
    const float* __restrict__ pw, const float* __restrict__ pb,
    unsigned short* __restrict__ th_hi, unsigned short* __restrict__ th_lo,
    unsigned short* __restrict__ ph_hi, unsigned short* __restrict__ ph_lo,
    unsigned short* __restrict__ gT)
{
    const int w    = threadIdx.x >> 6;
    const int lane = threadIdx.x & 63;
    const int lrow = lane & 15;
    const int kg   = lane >> 4;
    const int set  = blockIdx.z >> 3;      // 0: g, 1: theta, 2: phi
    const int b    = blockIdx.z & 7;
    const int c0   = blockIdx.y * 16;
    const int n0   = (blockIdx.x * 4 + w) * 16;

    const float* W  = (set == 0) ? gw : ((set == 1) ? tw : pw);
    const float* Bi = (set == 0) ? gb : ((set == 1) ? tb : pb);

    f32x4 acc = {0.f, 0.f, 0.f, 0.f};
    const float* xb = x + (size_t)b * CIN * NPOS;
#pragma unroll
    for (int ks = 0; ks < 8; ++ks) {
        const int k = ks * 32 + kg * 8;
        const float* wr = W + (c0 + lrow) * CIN + k;
        const float* xr = xb + (size_t)k * NPOS + n0 + lrow;
        bf16x8 ah, al, bh, bl;
#pragma unroll
        for (int j = 0; j < 8; ++j) {
            unsigned short h, l;
            splitbf(wr[j], h, l);
            ah[j] = (short)h; al[j] = (short)l;
            splitbf(xr[(size_t)j * NPOS], h, l);
            bh[j] = (short)h; bl[j] = (short)l;
        }
        acc = MFMA(ah, bh, acc);
        acc = MFMA(ah, bl, acc);
        acc = MFMA(al, bh, acc);
    }
    const int cbase = c0 + kg * 4;
    const int n = n0 + lrow;
    if (set == 0) {
#pragma unroll
        for (int r = 0; r < 4; ++r) {
            float v = acc[r] + Bi[cbase + r];
            gT[((size_t)b * IC + cbase + r) * NPOS + n] = f2bf(v);
        }
    } else {
        unsigned short* hi = (set == 1) ? th_hi : ph_hi;
        unsigned short* lo = (set == 1) ? th_lo : ph_lo;
        ushort4 vh, vl;
        splitbf(acc[0] + Bi[cbase + 0], vh.x, vl.x);
        splitbf(acc[1] + Bi[cbase + 1], vh.y, vl.y);
        splitbf(acc[2] + Bi[cbase + 2], vh.z, vl.z);
        splitbf(acc[3] + Bi[cbase + 3], vh.w, vl.w);
        size_t off = ((size_t)b * NPOS + n) * IC + cbase;
        *reinterpret_cast<ushort4*>(hi + off) = vh;
        *reinterpret_cast<ushort4*>(lo + off) = vl;
    }
}

// ---------------- GEMM1: f[n][m] = theta[n]·phi[m], split-bf16, 64x64/wave ----------------
__global__ __launch_bounds__(256) void k_gemm1(
    const unsigned short* __restrict__ th_hi, const unsigned short* __restrict__ th_lo,
    const unsigned short* __restrict__ ph_hi, const unsigned short* __restrict__ ph_lo,
    float* __restrict__ f, int b)
{
    const int w    = threadIdx.x >> 6;
    const int lane = threadIdx.x & 63;
    const int lrow = lane & 15;
    const int kg   = lane >> 4;
    const int tid  = blockIdx.x * 4 + w;      // 0..4095
    const int n0   = (tid >> 6) * 64;
    const int m0   = (tid & 63) * 64;

    const unsigned short* Ah = th_hi + (size_t)b * NPOS * IC;
    const unsigned short* Al = th_lo + (size_t)b * NPOS * IC;
    const unsigned short* Bh = ph_hi + (size_t)b * NPOS * IC;
    const unsigned short* Bl = ph_lo + (size_t)b * NPOS * IC;

    f32x4 acc[4][4] = {};
#pragma unroll
    for (int ks = 0; ks < 4; ++ks) {
        const int k = ks * 32 + kg * 8;
        bf16x8 ah[4], al[4], bh[4], bl[4];
#pragma unroll
        for (int i = 0; i < 4; ++i) {
            ah[i] = *reinterpret_cast<const bf16x8*>(Ah + (size_t)(n0 + i * 16 + lrow) * IC + k);
            al[i] = *reinterpret_cast<const bf16x8*>(Al + (size_t)(n0 + i * 16 + lrow) * IC + k);
            bh[i] = *reinterpret_cast<const bf16x8*>(Bh + (size_t)(m0 + i * 16 + lrow) * IC + k);
            bl[i] = *reinterpret_cast<const bf16x8*>(Bl + (size_t)(m0 + i * 16 + lrow) * IC + k);
        }
#pragma unroll
        for (int i = 0; i < 4; ++i)
#pragma unroll
            for (int j = 0; j < 4; ++j) {
                acc[i][j] = MFMA(ah[i], bh[j], acc[i][j]);
                acc[i][j] = MFMA(ah[i], bl[j], acc[i][j]);
                acc[i][j] = MFMA(al[i], bh[j], acc[i][j]);
            }
    }
#pragma unroll
    for (int i = 0; i < 4; ++i)
#pragma unroll
        for (int j = 0; j < 4; ++j)
#pragma unroll
            for (int r = 0; r < 4; ++r)
                f[(size_t)(n0 + i * 16 + kg * 4 + r) * NPOS + m0 + j * 16 + lrow] = acc[i][j][r];
}

// ---------------- column stats: softmax over n for each column m ----------------
__global__ __launch_bounds__(256) void k_stats(
    const float* __restrict__ f, float* __restrict__ cmax, float* __restrict__ crcp)
{
    __shared__ float smax[256], ssum[256];
    const int t = threadIdx.x;
    const int m = blockIdx.x * 64 + (t & 63);
    float vmax = -3.0e38f, vsum = 0.f;
    for (int r = (t >> 6); r < NPOS; r += 4) {
        float v = f[(size_t)r * NPOS + m];
        float nm = fmaxf(vmax, v);
        vsum = vsum * __expf(vmax - nm) + __expf(v - nm);
        vmax = nm;
    }
    smax[t] = vmax; ssum[t] = vsum;
    __syncthreads();
    if (t < 64) {
        float M = fmaxf(fmaxf(smax[t], smax[t + 64]), fmaxf(smax[t + 128], smax[t + 192]));
        float S = ssum[t] * __expf(smax[t] - M) + ssum[t + 64] * __expf(smax[t + 64] - M)
                + ssum[t + 128] * __expf(smax[t + 128] - M) + ssum[t + 192] * __expf(smax[t + 192] - M);
        cmax[blockIdx.x * 64 + t] = M;
        crcp[blockIdx.x * 64 + t] = 1.0f / S;
    }
}

// ---------------- GEMM2: partial[kc][c][n] = sum_m gT[c][m]·P[n][m] over K-chunk ----------------
__global__ __launch_bounds__(256) void k_gemm2(
    const float* __restrict__ f, const float* __restrict__ cmax, const float* __restrict__ crcp,
    const unsigned short* __restrict__ gT, float* __restrict__ partial, int b)
{
    const int w    = threadIdx.x >> 6;
    const int lane = threadIdx.x & 63;
    const int lrow = lane & 15;
    const int kg   = lane >> 4;
    const int gwid = blockIdx.x * 4 + w;      // 0..4095
    const int kc = gwid & 7;
    const int c0 = ((gwid >> 3) & 1) * 64;
    const int n0 = (gwid >> 4) * 16;
    const int mstart = kc * 512;

    const unsigned short* G = gT + (size_t)b * IC * NPOS;
    const float* frow = f + (size_t)(n0 + lrow) * NPOS;

    f32x4 acc[4] = {};
    for (int ks = 0; ks < 16; ++ks) {
        const int k = mstart + ks * 32 + kg * 8;
        fvec4 fv0 = *reinterpret_cast<const fvec4*>(frow + k);
        fvec4 fv1 = *reinterpret_cast<const fvec4*>(frow + k + 4);
        fvec4 cm0 = *reinterpret_cast<const fvec4*>(cmax + k);
        fvec4 cm1 = *reinterpret_cast<const fvec4*>(cmax + k + 4);
        fvec4 cr0 = *reinterpret_cast<const fvec4*>(crcp + k);
        fvec4 cr1 = *reinterpret_cast<const fvec4*>(crcp + k + 4);
        bf16x8 pbv;
#pragma unroll
        for (int j = 0; j < 4; ++j) {
            pbv[j]     = (short)f2bf(__expf(fv0[j] - cm0[j]) * cr0[j]);
            pbv[4 + j] = (short)f2bf(__expf(fv1[j] - cm1[j]) * cr1[j]);
        }
        bf16x8 a[4];
#pragma unroll
        for (int i = 0; i < 4; ++i)
            a[i] = *reinterpret_cast<const bf16x8*>(G + (size_t)(c0 + i * 16 + lrow) * NPOS + k);
#pragma unroll
        for (int i = 0; i < 4; ++i)
            acc[i] = MFMA(a[i], pbv, acc[i]);
    }
#pragma unroll
    for (int i = 0; i < 4; ++i)
#pragma unroll
        for (int r = 0; r < 4; ++r)
            partial[((size_t)kc * IC + c0 + i * 16 + kg * 4 + r) * NPOS + n0 + lrow] = acc[i][r];
}

// ---------------- reduce partials -> yT bf16 ----------------
__global__ __launch_bounds__(256) void k_reduce(
    const float* __restrict__ partial, unsigned short* __restrict__ yT, int b)
{
    const int idx = blockIdx.x * 256 + threadIdx.x;   // over IC*NPOS/4
    const fvec4* p = reinterpret_cast<const fvec4*>(partial);
    fvec4 s = p[idx];
#pragma unroll
    for (int kc = 1; kc < 8; ++kc) {
        fvec4 v = p[(size_t)kc * (IC * NPOS / 4) + idx];
        s[0] += v[0]; s[1] += v[1]; s[2] += v[2]; s[3] += v[3];
    }
    ushort4 o;
    o.x = f2bf(s[0]); o.y = f2bf(s[1]); o.z = f2bf(s[2]); o.w = f2bf(s[3]);
    *reinterpret_cast<ushort4*>(yT + (size_t)b * IC * NPOS + (size_t)idx * 4) = o;
}

// ---------------- final conv + residual: out[b][o][n] = x + Wb[o] + sum_ic W[o][ic] yT[ic][n] ----------------
__global__ __launch_bounds__(256) void k_conv(
    const float* __restrict__ x, const float* __restrict__ Ww, const float* __restrict__ Wb,
    const unsigned short* __restrict__ yT, float* __restrict__ out)
{
    const int w    = threadIdx.x >> 6;
    const int lane = threadIdx.x & 63;
    const int lrow = lane & 15;
    const int kg   = lane >> 4;
    const int b  = blockIdx.z;
    const int o0 = blockIdx.y * 16;
    const int n0 = (blockIdx.x * 4 + w) * 16;

    const unsigned short* Y = yT + (size_t)b * IC * NPOS;
    f32x4 acc = {0.f, 0.f, 0.f, 0.f};
#pragma unroll
    for (int ks = 0; ks < 4; ++ks) {
        const int k = ks * 32 + kg * 8;
        const float* wr = Ww + (o0 + lrow) * IC + k;
        bf16x8 av, bv;
#pragma unroll
        for (int j = 0; j < 8; ++j) {
            av[j] = (short)f2bf(wr[j]);
            bv[j] = (short)Y[(size_t)(k + j) * NPOS + n0 + lrow];
        }
        acc = MFMA(av, bv, acc);
    }
    const int n = n0 + lrow;
#pragma unroll
    for (int r = 0; r < 4; ++r) {
        const int o = o0 + kg * 4 + r;
        const size_t off = ((size_t)b * CIN + o) * NPOS + n;
        out[off] = acc[r] + x[off] + Wb[o];
    }
}

extern "C" void kernel_launch(void* const* d_in, const int* in_sizes, int n_in,
                              void* d_out, int out_size, void* d_ws, size_t ws_size,
                              hipStream_t stream)
{
    const float* x  = (const float*)d_in[0];
    const float* gw = (const float*)d_in[1];
    const float* gb = (const float*)d_in[2];
    const float* tw = (const float*)d_in[3];
    const float* tb = (const float*)d_in[4];
    const float* pw = (const float*)d_in[5];
    const float* pb = (const float*)d_in[6];
    const float* Ww = (const float*)d_in[7];
    const float* Wb = (const float*)d_in[8];
    float* out = (float*)d_out;

    char* ws = (char*)d_ws;
    size_t off = 0;
    auto alloc = [&](size_t bytes) -> char* {
        char* p = ws + off;
        off += (bytes + 255) & ~(size_t)255;
        return p;
    };
    const size_t projB = (size_t)NB * NPOS * IC * 2;           // 8 MB each
    unsigned short* th_hi = (unsigned short*)alloc(projB);
    unsigned short* th_lo = (unsigned short*)alloc(projB);
    unsigned short* ph_hi = (unsigned short*)alloc(projB);
    unsigned short* ph_lo = (unsigned short*)alloc(projB);
    unsigned short* gT    = (unsigned short*)alloc(projB);
    float* f       = (float*)alloc((size_t)NPOS * NPOS * 4);   // 64 MB (per-batch reuse)
    float* cmax    = (float*)alloc((size_t)NPOS * 4);
    float* crcp    = (float*)alloc((size_t)NPOS * 4);
    float* partial = (float*)alloc((size_t)8 * IC * NPOS * 4); // 16 MB (per-batch reuse)
    unsigned short* yT = (unsigned short*)alloc(projB);        // 8 MB

    // projections for all batches & all three weight sets
    k_proj<<<dim3(64, 8, 24), 256, 0, stream>>>(x, gw, gb, tw, tb, pw, pb,
                                                th_hi, th_lo, ph_hi, ph_lo, gT);

    for (int b = 0; b < NB; ++b) {
        k_gemm1<<<1024, 256, 0, stream>>>(th_hi, th_lo, ph_hi, ph_lo, f, b);
        k_stats<<<64, 256, 0, stream>>>(f, cmax, crcp);
        k_gemm2<<<1024, 256, 0, stream>>>(f, cmax, crcp, gT, partial, b);
        k_reduce<<<512, 256, 0, stream>>>(partial, yT, b);
    }
    k_conv<<<dim3(64, 16, 8), 256, 0, stream>>>(x, Ww, Wb, yT, out);
}

// Round 2
// 1054.084 us; speedup vs baseline: 3.0685x; 3.0685x over previous
//
#include <hip/hip_runtime.h>
#include <hip/hip_bf16.h>

// NonLocalBlock2D: x[8,256,64,64] fp32
//   theta/phi/g = 1x1 conv (C=256 -> IC=128)
//   f[n][m] = theta[n]·phi[m]; P = softmax over n (per column m)
//   y[n] = sum_m P[n][m] g[m];  out = W·y + b + x
// Pipeline (per batch for the big N×N stage, f buffer reused):
//   k_proj     : split-bf16 projections
//   k_gemm1    : f fp32 via split-bf16 MFMA; epilogue computes per-wave column
//                maxes and folds them into cmax[b][m] via deterministic atomicMax
//   k_colsum   : psum[16][m] = partial sums of exp(f-cmax) (256 blocks, float4)
//   k_colreduce: crcp[m] = 1/sum_i psum[i][m]
//   k_gemm2    : yT partials = gT·P (P from f on the fly)
//   k_reduce   : yT bf16 = sum of partials
//   k_conv     : out = W·yT + Wb + x

#define IC   128
#define CIN  256
#define NPOS 4096
#define NB   8

typedef __attribute__((ext_vector_type(8))) short bf16x8;
typedef __attribute__((ext_vector_type(4))) float f32x4;
typedef __attribute__((ext_vector_type(4))) float fvec4;

#define MFMA(a, b, c) __builtin_amdgcn_mfma_f32_16x16x32_bf16((a), (b), (c), 0, 0, 0)

static __device__ inline unsigned short f2bf(float f) {
    unsigned int u = __builtin_bit_cast(unsigned int, f);
    u += 0x7fffu + ((u >> 16) & 1u);   // RNE
    return (unsigned short)(u >> 16);
}
static __device__ inline float bf2f(unsigned short u) {
    unsigned int v = ((unsigned int)u) << 16;
    return __builtin_bit_cast(float, v);
}
static __device__ inline void splitbf(float v, unsigned short& hi, unsigned short& lo) {
    hi = f2bf(v);
    lo = f2bf(v - bf2f(hi));
}
// Deterministic float atomic max (max is exact & order-independent).
static __device__ inline void atomicMaxFloat(float* addr, float val) {
    if (val >= 0.0f)
        atomicMax((int*)addr, __float_as_int(val));
    else
        atomicMin((unsigned int*)addr, (unsigned int)__float_as_int(val));
}

// ---------------- projections: out[c][n] = sum_k w[c][k] x[k][n] + bias[c] ----------------
__global__ __launch_bounds__(256) void k_proj(
    const float* __restrict__ x,
    const float* __restrict__ gw, const float* __restrict__ gb,
    const float* __restrict__ tw, const float* __restrict__ tb,
    const float* __restrict__ pw, const float* __restrict__ pb,
    unsigned short* __restrict__ th_hi, unsigned short* __restrict__ th_lo,
    unsigned short* __restrict__ ph_hi, unsigned short* __restrict__ ph_lo,
    unsigned short* __restrict__ gT)
{
    const int w    = threadIdx.x >> 6;
    const int lane = threadIdx.x & 63;
    const int lrow = lane & 15;
    const int kg   = lane >> 4;
    const int set  = blockIdx.z >> 3;      // 0: g, 1: theta, 2: phi
    const int b    = blockIdx.z & 7;
    const int c0   = blockIdx.y * 16;
    const int n0   = (blockIdx.x * 4 + w) * 16;

    const float* W  = (set == 0) ? gw : ((set == 1) ? tw : pw);
    const float* Bi = (set == 0) ? gb : ((set == 1) ? tb : pb);

    f32x4 acc = {0.f, 0.f, 0.f, 0.f};
    const float* xb = x + (size_t)b * CIN * NPOS;
#pragma unroll
    for (int ks = 0; ks < 8; ++ks) {
        const int k = ks * 32 + kg * 8;
        const float* wr = W + (c0 + lrow) * CIN + k;
        const float* xr = xb + (size_t)k * NPOS + n0 + lrow;
        bf16x8 ah, al, bh, bl;
#pragma unroll
        for (int j = 0; j < 8; ++j) {
            unsigned short h, l;
            splitbf(wr[j], h, l);
            ah[j] = (short)h; al[j] = (short)l;
            splitbf(xr[(size_t)j * NPOS], h, l);
            bh[j] = (short)h; bl[j] = (short)l;
        }
        acc = MFMA(ah, bh, acc);
        acc = MFMA(ah, bl, acc);
        acc = MFMA(al, bh, acc);
    }
    const int cbase = c0 + kg * 4;
    const int n = n0 + lrow;
    if (set == 0) {
#pragma unroll
        for (int r = 0; r < 4; ++r) {
            float v = acc[r] + Bi[cbase + r];
            gT[((size_t)b * IC + cbase + r) * NPOS + n] = f2bf(v);
        }
    } else {
        unsigned short* hi = (set == 1) ? th_hi : ph_hi;
        unsigned short* lo = (set == 1) ? th_lo : ph_lo;
        ushort4 vh, vl;
        splitbf(acc[0] + Bi[cbase + 0], vh.x, vl.x);
        splitbf(acc[1] + Bi[cbase + 1], vh.y, vl.y);
        splitbf(acc[2] + Bi[cbase + 2], vh.z, vl.z);
        splitbf(acc[3] + Bi[cbase + 3], vh.w, vl.w);
        size_t off = ((size_t)b * NPOS + n) * IC + cbase;
        *reinterpret_cast<ushort4*>(hi + off) = vh;
        *reinterpret_cast<ushort4*>(lo + off) = vl;
    }
}

// ---------------- init cmax for all batches ----------------
__global__ __launch_bounds__(256) void k_init_cmax(float* __restrict__ cmax)
{
    cmax[blockIdx.x * 256 + threadIdx.x] = -3.0e38f;
}

// ---- GEMM1: f[n][m] = theta[n]·phi[m]; epilogue folds column max into cmax ----
__global__ __launch_bounds__(256) void k_gemm1(
    const unsigned short* __restrict__ th_hi, const unsigned short* __restrict__ th_lo,
    const unsigned short* __restrict__ ph_hi, const unsigned short* __restrict__ ph_lo,
    float* __restrict__ f, float* __restrict__ cmax, int b)
{
    const int w    = threadIdx.x >> 6;
    const int lane = threadIdx.x & 63;
    const int lrow = lane & 15;
    const int kg   = lane >> 4;
    const int tid  = blockIdx.x * 4 + w;      // 0..4095
    const int n0   = (tid >> 6) * 64;
    const int m0   = (tid & 63) * 64;

    const unsigned short* Ah = th_hi + (size_t)b * NPOS * IC;
    const unsigned short* Al = th_lo + (size_t)b * NPOS * IC;
    const unsigned short* Bh = ph_hi + (size_t)b * NPOS * IC;
    const unsigned short* Bl = ph_lo + (size_t)b * NPOS * IC;

    f32x4 acc[4][4] = {};
#pragma unroll
    for (int ks = 0; ks < 4; ++ks) {
        const int k = ks * 32 + kg * 8;
        bf16x8 ah[4], al[4], bh[4], bl[4];
#pragma unroll
        for (int i = 0; i < 4; ++i) {
            ah[i] = *reinterpret_cast<const bf16x8*>(Ah + (size_t)(n0 + i * 16 + lrow) * IC + k);
            al[i] = *reinterpret_cast<const bf16x8*>(Al + (size_t)(n0 + i * 16 + lrow) * IC + k);
            bh[i] = *reinterpret_cast<const bf16x8*>(Bh + (size_t)(m0 + i * 16 + lrow) * IC + k);
            bl[i] = *reinterpret_cast<const bf16x8*>(Bl + (size_t)(m0 + i * 16 + lrow) * IC + k);
        }
#pragma unroll
        for (int i = 0; i < 4; ++i)
#pragma unroll
            for (int j = 0; j < 4; ++j) {
                acc[i][j] = MFMA(ah[i], bh[j], acc[i][j]);
                acc[i][j] = MFMA(ah[i], bl[j], acc[i][j]);
                acc[i][j] = MFMA(al[i], bh[j], acc[i][j]);
            }
    }
#pragma unroll
    for (int i = 0; i < 4; ++i)
#pragma unroll
        for (int j = 0; j < 4; ++j)
#pragma unroll
            for (int r = 0; r < 4; ++r)
                f[(size_t)(n0 + i * 16 + kg * 4 + r) * NPOS + m0 + j * 16 + lrow] = acc[i][j][r];

    // column max over this wave's 64 rows, for its 64 columns
#pragma unroll
    for (int j = 0; j < 4; ++j) {
        float cm = -3.0e38f;
#pragma unroll
        for (int i = 0; i < 4; ++i)
#pragma unroll
            for (int r = 0; r < 4; ++r)
                cm = fmaxf(cm, acc[i][j][r]);
        cm = fmaxf(cm, __shfl_xor(cm, 16));
        cm = fmaxf(cm, __shfl_xor(cm, 32));
        if (kg == 0)
            atomicMaxFloat(&cmax[m0 + j * 16 + lrow], cm);
    }
}

// ---------------- column partial sums of exp(f - cmax) ----------------
__global__ __launch_bounds__(256) void k_colsum(
    const float* __restrict__ f, const float* __restrict__ cmax, float* __restrict__ psum)
{
    // grid (16,16): cols [bx*256,+256), rows [by*256,+256)
    const int t    = threadIdx.x;
    const int c4   = t & 63;
    const int rsub = t >> 6;
    const int col  = blockIdx.x * 256 + c4 * 4;
    fvec4 cm = *reinterpret_cast<const fvec4*>(cmax + col);
    fvec4 s = {0.f, 0.f, 0.f, 0.f};
    const float* base = f + (size_t)(blockIdx.y * 256 + rsub) * NPOS + col;
#pragma unroll 8
    for (int it = 0; it < 64; ++it) {
        fvec4 v = *reinterpret_cast<const fvec4*>(base + (size_t)it * 4 * NPOS);
        s[0] += __expf(v[0] - cm[0]);
        s[1] += __expf(v[1] - cm[1]);
        s[2] += __expf(v[2] - cm[2]);
        s[3] += __expf(v[3] - cm[3]);
    }
    __shared__ fvec4 sm[256];
    sm[t] = s;
    __syncthreads();
    if (rsub == 0) {
        fvec4 a = sm[t], b = sm[t + 64], c = sm[t + 128], d = sm[t + 192];
        fvec4 o;
        o[0] = (a[0] + b[0]) + (c[0] + d[0]);
        o[1] = (a[1] + b[1]) + (c[1] + d[1]);
        o[2] = (a[2] + b[2]) + (c[2] + d[2]);
        o[3] = (a[3] + b[3]) + (c[3] + d[3]);
        *reinterpret_cast<fvec4*>(psum + (size_t)blockIdx.y * NPOS + col) = o;
    }
}

// ---------------- reduce column partial sums -> crcp ----------------
__global__ __launch_bounds__(256) void k_colreduce(
    const float* __restrict__ psum, float* __restrict__ crcp)
{
    const int m = blockIdx.x * 256 + threadIdx.x;
    float s = 0.f;
#pragma unroll
    for (int i = 0; i < 16; ++i)
        s += psum[(size_t)i * NPOS + m];
    crcp[m] = 1.0f / s;
}

// ---------------- GEMM2: partial[kc][c][n] = sum_m gT[c][m]·P[n][m] over K-chunk ----------------
__global__ __launch_bounds__(256) void k_gemm2(
    const float* __restrict__ f, const float* __restrict__ cmax, const float* __restrict__ crcp,
    const unsigned short* __restrict__ gT, float* __restrict__ partial, int b)
{
    const int w    = threadIdx.x >> 6;
    const int lane = threadIdx.x & 63;
    const int lrow = lane & 15;
    const int kg   = lane >> 4;
    const int gwid = blockIdx.x * 4 + w;      // 0..4095
    const int kc = gwid & 7;
    const int c0 = ((gwid >> 3) & 1) * 64;
    const int n0 = (gwid >> 4) * 16;
    const int mstart = kc * 512;

    const unsigned short* G = gT + (size_t)b * IC * NPOS;
    const float* frow = f + (size_t)(n0 + lrow) * NPOS;

    f32x4 acc[4] = {};
    for (int ks = 0; ks < 16; ++ks) {
        const int k = mstart + ks * 32 + kg * 8;
        fvec4 fv0 = *reinterpret_cast<const fvec4*>(frow + k);
        fvec4 fv1 = *reinterpret_cast<const fvec4*>(frow + k + 4);
        fvec4 cm0 = *reinterpret_cast<const fvec4*>(cmax + k);
        fvec4 cm1 = *reinterpret_cast<const fvec4*>(cmax + k + 4);
        fvec4 cr0 = *reinterpret_cast<const fvec4*>(crcp + k);
        fvec4 cr1 = *reinterpret_cast<const fvec4*>(crcp + k + 4);
        bf16x8 pbv;
#pragma unroll
        for (int j = 0; j < 4; ++j) {
            pbv[j]     = (short)f2bf(__expf(fv0[j] - cm0[j]) * cr0[j]);
            pbv[4 + j] = (short)f2bf(__expf(fv1[j] - cm1[j]) * cr1[j]);
        }
        bf16x8 a[4];
#pragma unroll
        for (int i = 0; i < 4; ++i)
            a[i] = *reinterpret_cast<const bf16x8*>(G + (size_t)(c0 + i * 16 + lrow) * NPOS + k);
#pragma unroll
        for (int i = 0; i < 4; ++i)
            acc[i] = MFMA(a[i], pbv, acc[i]);
    }
#pragma unroll
    for (int i = 0; i < 4; ++i)
#pragma unroll
        for (int r = 0; r < 4; ++r)
            partial[((size_t)kc * IC + c0 + i * 16 + kg * 4 + r) * NPOS + n0 + lrow] = acc[i][r];
}

// ---------------- reduce partials -> yT bf16 ----------------
__global__ __launch_bounds__(256) void k_reduce(
    const float* __restrict__ partial, unsigned short* __restrict__ yT, int b)
{
    const int idx = blockIdx.x * 256 + threadIdx.x;   // over IC*NPOS/4
    const fvec4* p = reinterpret_cast<const fvec4*>(partial);
    fvec4 s = p[idx];
#pragma unroll
    for (int kc = 1; kc < 8; ++kc) {
        fvec4 v = p[(size_t)kc * (IC * NPOS / 4) + idx];
        s[0] += v[0]; s[1] += v[1]; s[2] += v[2]; s[3] += v[3];
    }
    ushort4 o;
    o.x = f2bf(s[0]); o.y = f2bf(s[1]); o.z = f2bf(s[2]); o.w = f2bf(s[3]);
    *reinterpret_cast<ushort4*>(yT + (size_t)b * IC * NPOS + (size_t)idx * 4) = o;
}

// ---------------- final conv + residual ----------------
__global__ __launch_bounds__(256) void k_conv(
    const float* __restrict__ x, const float* __restrict__ Ww, const float* __restrict__ Wb,
    const unsigned short* __restrict__ yT, float* __restrict__ out)
{
    const int w    = threadIdx.x >> 6;
    const int lane = threadIdx.x & 63;
    const int lrow = lane & 15;
    const int kg   = lane >> 4;
    const int b  = blockIdx.z;
    const int o0 = blockIdx.y * 16;
    const int n0 = (blockIdx.x * 4 + w) * 16;

    const unsigned short* Y = yT + (size_t)b * IC * NPOS;
    f32x4 acc = {0.f, 0.f, 0.f, 0.f};
#pragma unroll
    for (int ks = 0; ks < 4; ++ks) {
        const int k = ks * 32 + kg * 8;
        const float* wr = Ww + (o0 + lrow) * IC + k;
        bf16x8 av, bv;
#pragma unroll
        for (int j = 0; j < 8; ++j) {
            av[j] = (short)f2bf(wr[j]);
            bv[j] = (short)Y[(size_t)(k + j) * NPOS + n0 + lrow];
        }
        acc = MFMA(av, bv, acc);
    }
    const int n = n0 + lrow;
#pragma unroll
    for (int r = 0; r < 4; ++r) {
        const int o = o0 + kg * 4 + r;
        const size_t off = ((size_t)b * CIN + o) * NPOS + n;
        out[off] = acc[r] + x[off] + Wb[o];
    }
}

extern "C" void kernel_launch(void* const* d_in, const int* in_sizes, int n_in,
                              void* d_out, int out_size, void* d_ws, size_t ws_size,
                              hipStream_t stream)
{
    const float* x  = (const float*)d_in[0];
    const float* gw = (const float*)d_in[1];
    const float* gb = (const float*)d_in[2];
    const float* tw = (const float*)d_in[3];
    const float* tb = (const float*)d_in[4];
    const float* pw = (const float*)d_in[5];
    const float* pb = (const float*)d_in[6];
    const float* Ww = (const float*)d_in[7];
    const float* Wb = (const float*)d_in[8];
    float* out = (float*)d_out;

    char* ws = (char*)d_ws;
    size_t off = 0;
    auto alloc = [&](size_t bytes) -> char* {
        char* p = ws + off;
        off += (bytes + 255) & ~(size_t)255;
        return p;
    };
    const size_t projB = (size_t)NB * NPOS * IC * 2;           // 8 MB each
    unsigned short* th_hi = (unsigned short*)alloc(projB);
    unsigned short* th_lo = (unsigned short*)alloc(projB);
    unsigned short* ph_hi = (unsigned short*)alloc(projB);
    unsigned short* ph_lo = (unsigned short*)alloc(projB);
    unsigned short* gT    = (unsigned short*)alloc(projB);
    float* f       = (float*)alloc((size_t)NPOS * NPOS * 4);   // 64 MB (per-batch reuse)
    float* cmax    = (float*)alloc((size_t)NB * NPOS * 4);     // per batch
    float* crcp    = (float*)alloc((size_t)NPOS * 4);          // per-batch reuse
    float* psum    = (float*)alloc((size_t)16 * NPOS * 4);     // per-batch reuse
    float* partial = (float*)alloc((size_t)8 * IC * NPOS * 4); // 16 MB (per-batch reuse)
    unsigned short* yT = (unsigned short*)alloc(projB);        // 8 MB

    // projections for all batches & all three weight sets
    k_proj<<<dim3(64, 8, 24), 256, 0, stream>>>(x, gw, gb, tw, tb, pw, pb,
                                                th_hi, th_lo, ph_hi, ph_lo, gT);
    k_init_cmax<<<NB * NPOS / 256, 256, 0, stream>>>(cmax);

    for (int b = 0; b < NB; ++b) {
        float* cm = cmax + (size_t)b * NPOS;
        k_gemm1<<<1024, 256, 0, stream>>>(th_hi, th_lo, ph_hi, ph_lo, f, cm, b);
        k_colsum<<<dim3(16, 16), 256, 0, stream>>>(f, cm, psum);
        k_colreduce<<<16, 256, 0, stream>>>(psum, crcp);
        k_gemm2<<<1024, 256, 0, stream>>>(f, cm, crcp, gT, partial, b);
        k_reduce<<<512, 256, 0, stream>>>(partial, yT, b);
    }
    k_conv<<<dim3(64, 16, 8), 256, 0, stream>>>(x, Ww, Wb, yT, out);
}